// Round 1
// 158.198 us; speedup vs baseline: 1.0539x; 1.0539x over previous
//
#include <hip/hip_runtime.h>

#define NB   64
#define NT   256
#define NI   512
#define NO   512
#define NOBS 128
#define ETA  0.01f

typedef __attribute__((ext_vector_type(8))) short bf16x8;
typedef __attribute__((ext_vector_type(4))) float f32x4;

#define X4_COUNT  (NB*NT*NI/4)
#define WG4_COUNT (NB*NOBS*NI/4)
#define K0_TOTAL  (X4_COUNT + WG4_COUNT)

__device__ __forceinline__ unsigned short f2bf(float f) {
    unsigned int u = __float_as_uint(f);
    return (unsigned short)((u + 0x7fffu + ((u >> 16) & 1u)) >> 16); // RNE
}

// ---------------- K0: X -> bf16 ; gather obs rows of W -> bf16 ----------------
__global__ __launch_bounds__(256)
void k0_convert(const float* __restrict__ X, const float* __restrict__ Wi,
                const int* __restrict__ obs,
                unsigned short* __restrict__ Xb, unsigned short* __restrict__ Wg)
{
    int idx = blockIdx.x * 256 + threadIdx.x;
    const int stride = gridDim.x * 256;
    for (; idx < K0_TOTAL; idx += stride) {
        float4 v; ushort4* dst;
        if (idx < X4_COUNT) {
            v = ((const float4*)X)[idx];
            dst = (ushort4*)Xb + idx;
        } else {
            int g = idx - X4_COUNT;
            int row = g >> 7, pos = g & 127;
            int b = row >> 7, j = row & 127;
            v = ((const float4*)(Wi + ((size_t)b * NO + obs[j]) * NI))[pos];
            dst = (ushort4*)Wg + ((size_t)row * 128 + pos);
        }
        *dst = make_ushort4(f2bf(v.x), f2bf(v.y), f2bf(v.z), f2bf(v.w));
    }
}

// ---------------- K1: LDS-tiled bf16 MFMA GEMM ----------------
// 5 blocks/batch: sub 0->(0,0) 1->(1,0) 2->(1,1) of G -> writes bf16 Gh (all)
// + fp32 Gd for diagonal 16-tiles. sub 3..4 -> P0 row-blocks {0,1} (fp32).
__global__ __launch_bounds__(256)
void k1_gemm(const unsigned short* __restrict__ Xb,
             const unsigned short* __restrict__ Wg,
             float* __restrict__ Gd, unsigned short* __restrict__ Gh,
             float* __restrict__ P0)
{
    __shared__ unsigned short As[128 * 64];
    __shared__ unsigned short Bs[128 * 64];

    const int tid  = threadIdx.x;
    const int lane = tid & 63;
    const int wv   = tid >> 6;
    const int l16  = lane & 15;
    const int quad = lane >> 4;

    const int b   = blockIdx.x & 63;   // same-batch blocks -> same XCD
    const int sub = blockIdx.x >> 6;   // 0..4

    const unsigned short* xbB = Xb + (size_t)b * NT * NI;
    const unsigned short *aRows, *bRows;
    int bm = 0, bn = 0;
    if (sub < 3) {
        bm = (sub >= 1) ? 1 : 0;
        bn = (sub == 2) ? 1 : 0;
        aRows = xbB + (size_t)bm * 128 * NI;
        bRows = xbB + (size_t)bn * 128 * NI;
    } else {
        const int pb = sub - 3;
        bm = pb;
        aRows = xbB + (size_t)pb * 128 * NI;
        bRows = Wg + (size_t)b * NOBS * NI;
    }

    const int wm = (wv >> 1) * 64;
    const int wn = (wv & 1) * 64;

    f32x4 acc[4][4] = {};

    for (int kb = 0; kb < NI / 64; ++kb) {
        __syncthreads();
#pragma unroll
        for (int it = 0; it < 4; ++it) {
            const int s = it * 256 + tid;
            const int m = s >> 3, c = s & 7;
            const int slot = m * 64 + ((c ^ (m & 7)) * 8);
            const size_t goff = (size_t)m * NI + kb * 64 + c * 8;
            *(bf16x8*)&As[slot] = *(const bf16x8*)(aRows + goff);
            *(bf16x8*)&Bs[slot] = *(const bf16x8*)(bRows + goff);
        }
        __syncthreads();
#pragma unroll
        for (int ks = 0; ks < 2; ++ks) {
            const int q = ks * 4 + quad;
            bf16x8 af[4], bfr[4];
#pragma unroll
            for (int mt = 0; mt < 4; ++mt) {
                const int m = wm + mt * 16 + l16;
                af[mt] = *(const bf16x8*)&As[m * 64 + ((q ^ (m & 7)) * 8)];
            }
#pragma unroll
            for (int nt = 0; nt < 4; ++nt) {
                const int n = wn + nt * 16 + l16;
                bfr[nt] = *(const bf16x8*)&Bs[n * 64 + ((q ^ (n & 7)) * 8)];
            }
#pragma unroll
            for (int mt = 0; mt < 4; ++mt)
#pragma unroll
                for (int nt = 0; nt < 4; ++nt)
                    acc[mt][nt] = __builtin_amdgcn_mfma_f32_16x16x32_bf16(
                        af[mt], bfr[nt], acc[mt][nt], 0, 0, 0);
        }
    }

    if (sub < 3) {
        unsigned short* GhB = Gh + ((size_t)b << 16);
        float* GdB = Gd + ((size_t)b << 12);
#pragma unroll
        for (int mt = 0; mt < 4; ++mt)
#pragma unroll
            for (int nt = 0; nt < 4; ++nt) {
                const int gcol = bn * 128 + wn + nt * 16 + l16;
#pragma unroll
                for (int r = 0; r < 4; ++r) {
                    const int grow = bm * 128 + wm + mt * 16 + quad * 4 + r;
                    const float v = acc[mt][nt][r];
                    GhB[(size_t)grow * 256 + gcol] = f2bf(v);
                    if ((grow >> 4) == (gcol >> 4))
                        GdB[((grow >> 4) << 8) + ((grow & 15) << 4) + (gcol & 15)] = v;
                }
            }
    } else {
        float* Pb = P0 + (size_t)b * NT * NOBS + (size_t)bm * 128 * NOBS;
#pragma unroll
        for (int mt = 0; mt < 4; ++mt)
#pragma unroll
            for (int nt = 0; nt < 4; ++nt)
#pragma unroll
                for (int r = 0; r < 4; ++r)
                    Pb[(size_t)(wm + mt * 16 + quad * 4 + r) * NOBS
                       + wn + nt * 16 + l16] = acc[mt][nt][r];
    }
}

// ---------------- K2: latency-optimized MFMA blocked scan ----------------
// block = (b, 16 j's) -> 512 blocks (2/CU), 512 threads (8 waves).
// Wave w holds pre tiles T=2w,2w+1 as MFMA C-fragments.
// ONE barrier per chunk: {build B from ybf2 | prefetch A(T,c+1) | rank-16 MFMA
// updates T>c | owner((c+1)>>1) dumps tile c+1 via LDS and runs the serial
// sigmoid scan (overlapping the other waves' lazy updates) | barrier}.
__global__ __launch_bounds__(512, 4)
void k2_scan(const float* __restrict__ Gd, const unsigned short* __restrict__ Gh,
             const float* __restrict__ P0, float* __restrict__ out)
{
    __shared__ float gdiag[16 * 16 * 16];      // 16 KB [c][u][v] fp32
    __shared__ float preS[16 * 17];            // padded transpose buffer
    __shared__ unsigned int ybf2[2 * 8 * 16];  // ping-pong packed eta*y pairs

    const int tid  = threadIdx.x;
    const int lane = tid & 63;
    const int l16  = lane & 15;
    const int quad = lane >> 4;
    const int w    = __builtin_amdgcn_readfirstlane(tid >> 6);

    const int b  = blockIdx.x & 63;            // same-batch blocks -> same XCD
    const int jg = blockIdx.x >> 6;            // 0..7 col-groups of 16

    const float* Pb = P0 + (size_t)b * NT * NOBS + jg * 16;
    const unsigned short* GhB = Gh + ((size_t)b << 16);
    float* ob = out + (size_t)b * NT * NOBS + jg * 16;

    // stage fp32 diag tiles (Gd[b] is 16 KB contiguous).
    // chunk-0 tile (floats 0..255) is written by wave 0 itself (tids 0..63),
    // so the pre-loop scan only needs a wave-local lgkmcnt wait.
    {
        const f32x4* gs = (const f32x4*)(Gd + ((size_t)b << 12));
        ((f32x4*)gdiag)[tid]       = gs[tid];
        ((f32x4*)gdiag)[512 + tid] = gs[512 + tid];
    }

    // init pre C-fragments from P0: D[m=quad*4+r][n=l16]
    f32x4 acc[2];
#pragma unroll
    for (int s2 = 0; s2 < 2; ++s2)
#pragma unroll
        for (int r = 0; r < 4; ++r)
            acc[s2][r] = Pb[(size_t)(w * 32 + s2 * 16 + quad * 4 + r) * NOBS + l16];

    const int T0 = 2 * w, T1 = 2 * w + 1;

    union AB { bf16x8 v; unsigned int d[4]; };
    AB Acur0, Acur1, Anext0, Anext1;
#pragma unroll
    for (int p2 = 0; p2 < 4; ++p2) {
        Acur0.d[p2] = 0; Acur1.d[p2] = 0; Anext0.d[p2] = 0; Anext1.d[p2] = 0;
    }
    // prefetch A(T, c=0)
    if (quad < 2) {
        if (T0 > 0)
            Acur0.v = *(const bf16x8*)(GhB + (size_t)(T0 * 16 + l16) * 256 + quad * 8);
        Acur1.v = *(const bf16x8*)(GhB + (size_t)(T1 * 16 + l16) * 256 + quad * 8);
    }

    // dump one 16x16 fp32 tile through LDS, then 16 lanes run the serial
    // sigmoid scan for chunk c (intra-wave only: lgkmcnt wait, no barrier)
    auto scan_chunk = [&](const int c, const f32x4 a) {
#pragma unroll
        for (int r = 0; r < 4; ++r)
            preS[(quad * 4 + r) * 17 + l16] = a[r];
        asm volatile("s_waitcnt lgkmcnt(0)" ::: "memory");
        if (lane < 16) {
            const int j = lane;
            const int cp = c & 1;
            float p[16];
#pragma unroll
            for (int u = 0; u < 16; ++u) p[u] = preS[u * 17 + j];
            const float* gdc = gdiag + c * 256;
            float eprev = 0.f;
#pragma unroll
            for (int u = 0; u < 16; ++u) {
                const float y = __builtin_amdgcn_rcpf(1.f + __expf(-p[u]));
                ob[(size_t)(c * 16 + u) * NOBS + j] = y;
                const float e = ETA * y;
#pragma unroll
                for (int v = u + 1; v < 16; ++v)
                    p[v] = fmaf(e, gdc[u * 16 + v], p[v]);
                if (u & 1)
                    ybf2[cp * 128 + (u >> 1) * 16 + j] =
                        (unsigned)f2bf(eprev) | ((unsigned)f2bf(e) << 16);
                else
                    eprev = e;
            }
        }
    };

    // chunk 0: owner = wave 0 (tile 0 is P0-only, no updates needed)
    if (w == 0)
        scan_chunk(0, acc[0]);
    __syncthreads();

#pragma unroll
    for (int c = 0; c < 15; ++c) {
        if (T1 > c) {   // wave still has live tiles
            // B fragment from ybf2[c&1]: B[k=u][n=j], upper K-half zero
            AB B;
#pragma unroll
            for (int p2 = 0; p2 < 4; ++p2) B.d[p2] = 0;
            if (quad < 2) {
#pragma unroll
                for (int p2 = 0; p2 < 4; ++p2)
                    B.d[p2] = ybf2[(c & 1) * 128 + (quad * 4 + p2) * 16 + l16];
            }
            // prefetch A(T, c+1) for next iteration (covered by MFMA+scan)
#pragma unroll
            for (int p2 = 0; p2 < 4; ++p2) { Anext0.d[p2] = 0; Anext1.d[p2] = 0; }
            if (quad < 2) {
                if (T0 > c + 1)
                    Anext0.v = *(const bf16x8*)(GhB + (size_t)(T0 * 16 + l16) * 256
                                                + (c + 1) * 16 + quad * 8);
                if (T1 > c + 1)
                    Anext1.v = *(const bf16x8*)(GhB + (size_t)(T1 * 16 + l16) * 256
                                                + (c + 1) * 16 + quad * 8);
            }
            // rank-16 updates of this wave's future tiles
            if (T0 > c)
                acc[0] = __builtin_amdgcn_mfma_f32_16x16x32_bf16(
                    Acur0.v, B.v, acc[0], 0, 0, 0);
            acc[1] = __builtin_amdgcn_mfma_f32_16x16x32_bf16(
                Acur1.v, B.v, acc[1], 0, 0, 0);
            // owner of chunk c+1 scans it now (its own tile is fully updated),
            // overlapping the other waves' update work until the barrier
            if (w == ((c + 1) >> 1))
                scan_chunk(c + 1, acc[(c + 1) & 1]);
            Acur0 = Anext0;
            Acur1 = Anext1;
        }
        __syncthreads();
    }
}

extern "C" void kernel_launch(void* const* d_in, const int* in_sizes, int n_in,
                              void* d_out, int out_size, void* d_ws, size_t ws_size,
                              hipStream_t stream)
{
    const float* X   = (const float*)d_in[0];
    const float* Wi  = (const float*)d_in[1];
    const int*   obs = (const int*)d_in[2];
    float*       out = (float*)d_out;

    float*          Gd = (float*)d_ws;                                  //  1 MB
    float*          P0 = (float*)((char*)d_ws + (1u << 20));            //  8 MB
    unsigned short* Gh = (unsigned short*)((char*)d_ws + (9u << 20));   //  8 MB
    unsigned short* Xb = (unsigned short*)((char*)d_ws + (17u << 20));  // 16 MB
    unsigned short* Wg = (unsigned short*)((char*)d_ws + (33u << 20));  //  8 MB

    hipLaunchKernelGGL(k0_convert, dim3(3072), dim3(256), 0, stream,
                       X, Wi, obs, Xb, Wg);
    hipLaunchKernelGGL(k1_gemm, dim3(NB * 5), dim3(256), 0, stream,
                       Xb, Wg, Gd, Gh, P0);
    hipLaunchKernelGGL(k2_scan, dim3(NB * 8), dim3(512), 0, stream,
                       Gd, Gh, P0, out);
}